// Round 14
// baseline (468.023 us; speedup 1.0000x reference)
//
#include <hip/hip_runtime.h>
#include <hip/hip_bf16.h>
#include <math.h>
#include <cstddef>

// ---------------------------------------------------------------------------
// Workspace (float offsets). Total ~151 MB.
//   Xmb   : bf16 [4096 s][1024 k]   floats [0 .. 2,097,152)
//   Cb    : bf16 [4096 co][1024 k]  floats [2,097,152 .. 4,194,304)
//   biasc : f32 [4096]              floats [4,194,304 ..)
//   b_buf : f32 [4096]              floats [4,198,400 ..)
//   b_rot : f32 [4096]              floats [4,202,496 ..)
//   P     : f32 [4096 s][4096 co]   floats [4,206,592 .. 20,983,808)
//   Pb    : bf16 [4096][4096]       floats [20,983,808 .. 29,372,416)
//   prwb  : bf16 [4096][4096]       floats [29,372,416 .. 37,761,024)
// k-index: k = ci*324 + m*18 + n  (ci<3, m<18, n<18; 972 real + 52 zero pad)
// ---------------------------------------------------------------------------
#define CB_F     2097152ull
#define BIASC_F  4194304ull
#define BBUF_F   4198400ull
#define BROT_F   4202496ull
#define P_F      4206592ull
#define PB_F     20983808ull
#define PRWB_F   29372416ull
#define ATTN_OFF 16777216ull

typedef __attribute__((ext_vector_type(8))) short bf16x8;
typedef __attribute__((ext_vector_type(4))) float f32x4;
typedef __attribute__((ext_vector_type(2))) float f32x2;

#define GLOAD16(gsrc, ldst) \
  __builtin_amdgcn_global_load_lds((const __attribute__((address_space(1))) void*)(gsrc), \
                                   (__attribute__((address_space(3))) void*)(ldst), 16, 0, 0)

// ===========================================================================
// Kernel FRONT (one dispatch, 7169 blocks x 256 thr):
//   blocks [0,2048)      : C-matrix (k_cmat v8 verbatim -- the 444us winner)
//   blocks [2048,6144)   : Xmap (s = bid - 2048)
//   block  6144          : x_feat conv + b-chain
//   blocks (6144,7168]   : cast prw f32 -> prwb bf16 (grid-stride)
// All parts mutually independent; consumers (GEMMs/attn) launch after.
// ===========================================================================
__global__ __launch_bounds__(256) void k_front(
    const float* __restrict__ pw, const float* __restrict__ rcw,
    const float* __restrict__ pb, const float* __restrict__ rcb,
    __hip_bfloat16* __restrict__ Cb, float* __restrict__ biasc,
    const float* __restrict__ x, __hip_bfloat16* __restrict__ Xmb,
    const float* __restrict__ xcw, const float* __restrict__ xcb,
    const float* __restrict__ bpw, const float* __restrict__ bpb,
    const float* __restrict__ nbg, const float* __restrict__ nbb,
    float* __restrict__ b_buf, float* __restrict__ b_rot,
    const float* __restrict__ prw, __hip_bfloat16* __restrict__ prwb)
{
    int t = threadIdx.x;
    int bid = blockIdx.x;

    if (bid < 2048) {
        // ================= cmat v8 (verbatim from round-12 winner) =========
        __shared__ __attribute__((aligned(16))) float Ws[64 * 28];      // 7.2 KB
        __shared__ __attribute__((aligned(16))) float Dz[20 * 20 * 12]; // 19.2 KB
        __shared__ float red[4];
        int w = t >> 6, lane = t & 63;
        int co_idx = w >> 1, half = w & 1;
        int co = bid * 2 + co_idx;
        const float* pwc = pw + (size_t)co * 16384;

        for (int i = t; i < 1728; i += 256) Ws[(i / 27) * 28 + (i % 27)] = rcw[i];
        if (t < 64) Ws[t * 28 + 27] = rcb[t];
        for (int i = t; i < 4800; i += 256) Dz[i] = 0.0f;
        __syncthreads();

        float D[2][27];
        #pragma unroll
        for (int q = 0; q < 2; ++q)
            #pragma unroll
            for (int j = 0; j < 27; ++j) D[q][j] = 0.0f;
        float bsum = 0.0f;
        const float* src = pwc + half * 128 + 2 * lane;
        #pragma unroll 4
        for (int c = 0; c < 64; ++c) {
            f32x2 v = *(const f32x2*)(src + c * 256);
            const f32x4* wp = (const f32x4*)&Ws[c * 28];
            #pragma unroll
            for (int q7 = 0; q7 < 7; ++q7) {
                f32x4 wv = wp[q7];                       // uniform ds_read_b128
                #pragma unroll
                for (int e = 0; e < 4; ++e) {
                    int j = q7 * 4 + e;
                    if (j < 27) {
                        D[0][j] = fmaf(wv[e], v.x, D[0][j]);
                        D[1][j] = fmaf(wv[e], v.y, D[1][j]);
                    } else {
                        bsum = fmaf(wv[e], v.x + v.y, bsum);
                    }
                }
            }
        }
        #pragma unroll
        for (int s = 32; s; s >>= 1) bsum += __shfl_down(bsum, s, 64);
        if (lane == 0) red[w] = bsum;
        __syncthreads();
        if (t < 2) biasc[bid * 2 + t] = pb[bid * 2 + t] + red[t * 2] + red[t * 2 + 1];

        for (int p = 0; p < 6; ++p) {
            int pco = p / 3, ci = p % 3;
            __syncthreads();
            if (co_idx == pco) {
                #pragma unroll
                for (int q = 0; q < 2; ++q) {
                    int rs = half * 128 + 2 * lane + q;
                    int r = rs >> 4, s2 = rs & 15;
                    float* dst = &Dz[((r + 2) * 20 + (s2 + 2)) * 12];
                    #pragma unroll
                    for (int u = 0; u < 9; ++u) dst[u] = D[q][ci * 9 + u];
                }
            }
            __syncthreads();
            int cop = bid * 2 + pco;
            if (t < 162) {
                int m = t / 9, n0 = (t % 9) * 2;
                float a0 = 0.0f, a1 = 0.0f;
                #pragma unroll
                for (int ky = 0; ky < 3; ++ky)
                    #pragma unroll
                    for (int kx = 0; kx < 3; ++kx) {
                        int u = ky * 3 + kx;
                        const float* pz = &Dz[((m - ky + 2) * 20 + (n0 - kx + 2)) * 12 + u];
                        a0 += pz[0];
                        a1 += pz[12];
                    }
                size_t cb = (size_t)cop * 1024;
                Cb[cb + ci * 324 + m * 18 + n0]     = __float2bfloat16(a0);
                Cb[cb + ci * 324 + m * 18 + n0 + 1] = __float2bfloat16(a1);
            }
            if (ci == 0 && t >= 162 && t < 214)
                Cb[(size_t)cop * 1024 + 972 + (t - 162)] = __float2bfloat16(0.0f);
        }
        return;
    }

    if (bid > 6144) {
        // ================= cast prw -> prwb (1024 blocks, grid-stride) =====
        long base0 = ((long)(bid - 6145) * 256 + t) * 8;
        for (long i = base0; i < 16777216L; i += 2097152L) {
            float4 v0 = *(const float4*)(prw + i);
            float4 v1 = *(const float4*)(prw + i + 4);
            __hip_bfloat16 h[8] = {__float2bfloat16(v0.x), __float2bfloat16(v0.y),
                                   __float2bfloat16(v0.z), __float2bfloat16(v0.w),
                                   __float2bfloat16(v1.x), __float2bfloat16(v1.y),
                                   __float2bfloat16(v1.z), __float2bfloat16(v1.w)};
            *(ushort4*)(prwb + i)     = *(const ushort4*)h;
            *(ushort4*)(prwb + i + 4) = *(const ushort4*)(h + 4);
        }
        return;
    }

    // shared x tile for xmap / bchain paths
    __shared__ float xs[3][8][8];
    if (t < 192) xs[t / 64][(t / 8) % 8][t % 8] = x[t];
    __syncthreads();

    if (bid < 6144) {
        // ================= Xmap =================
        int s = bid - 2048, py = s >> 6, px = s & 63;
        __hip_bfloat16 out4[4];
        #pragma unroll
        for (int u = 0; u < 4; ++u) {
            int k = t * 4 + u;
            float val = 0.0f;
            if (k < 972) {
                int ci = k / 324, r = k % 324, m = r / 18, n = r % 18;
                int row = 16 * py + m - 1, col = 16 * px + n - 1;
                if (row >= 0 && row < 1024 && col >= 0 && col < 1024) {
                    float fu = (row + 0.5f) * 0.0078125f - 0.5f;
                    float fv = (col + 0.5f) * 0.0078125f - 0.5f;
                    float fi = floorf(fu), fj = floorf(fv);
                    float tu = fu - fi, tv = fv - fj;
                    int i0 = (int)fi, j0 = (int)fj;
                    int i0c = min(max(i0, 0), 7), i1c = min(max(i0 + 1, 0), 7);
                    int j0c = min(max(j0, 0), 7), j1c = min(max(j0 + 1, 0), 7);
                    val = (xs[ci][i0c][j0c] * (1.f - tv) + xs[ci][i0c][j1c] * tv) * (1.f - tu)
                        + (xs[ci][i1c][j0c] * (1.f - tv) + xs[ci][i1c][j1c] * tv) * tu;
                }
            }
            out4[u] = __float2bfloat16(val);
        }
        *(ushort4*)(Xmb + (size_t)s * 1024 + t * 4) = *(const ushort4*)out4;
        return;
    }

    // ================= bchain (bid == 6144) =================
    __shared__ float xf[64][8][8];
    for (int o = t; o < 4096; o += 256) {
        int c = o >> 6, i = (o >> 3) & 7, j = o & 7;
        float acc = xcb[c];
        for (int ic = 0; ic < 3; ++ic)
            for (int ky = 0; ky < 3; ++ky)
                for (int kx = 0; kx < 3; ++kx) {
                    int ii = i - 1 + ky, jj = j - 1 + kx;
                    if (ii >= 0 && ii < 8 && jj >= 0 && jj < 8)
                        acc = fmaf(xs[ic][ii][jj], xcw[((c * 3 + ic) * 3 + ky) * 3 + kx], acc);
                }
        xf[c][i][j] = acc;
    }
    __syncthreads();
    for (int idx = t; idx < 1024; idx += 256) {
        int wi = idx >> 8, h = (idx >> 4) & 15, pp = idx & 15;
        int pr = pp >> 2, pc = pp & 3;
        int gi = 4 * (wi >> 1) + pr, gj = 4 * (wi & 1) + pc;
        float v[4];
        #pragma unroll
        for (int d = 0; d < 4; ++d) v[d] = xf[h * 4 + d][gi][gj];
        float mu = 0.25f * (v[0] + v[1] + v[2] + v[3]);
        float var = 0.25f * ((v[0]-mu)*(v[0]-mu) + (v[1]-mu)*(v[1]-mu) +
                             (v[2]-mu)*(v[2]-mu) + (v[3]-mu)*(v[3]-mu));
        float inv = rsqrtf(var + 1e-5f);
        float xh[4];
        #pragma unroll
        for (int d = 0; d < 4; ++d) xh[d] = (v[d] - mu) * inv * nbg[d] + nbb[d];
        float bv[4];
        #pragma unroll
        for (int d = 0; d < 4; ++d) {
            float a = bpb[d];
            #pragma unroll
            for (int e = 0; e < 4; ++e) a = fmaf(xh[e], bpw[d * 4 + e], a);
            bv[d] = a;
        }
        #pragma unroll
        for (int d = 0; d < 4; ++d) b_buf[idx * 4 + d] = bv[d];
        float nn = sqrtf(bv[0]*bv[0] + bv[1]*bv[1] + bv[2]*bv[2] + bv[3]*bv[3]);
        float in2 = 1.0f / fmaxf(nn, 1e-12f);
        float bn[4];
        #pragma unroll
        for (int d = 0; d < 4; ++d) bn[d] = bv[d] * in2;
        float s0, c0, s1, c1;
        sincosf((float)pr, &s0, &c0);
        sincosf((float)pc, &s1, &c1);
        b_rot[idx * 4 + 0] = bn[0] * c0 - bn[1] * s0;
        b_rot[idx * 4 + 1] = bn[0] * s0 + bn[1] * c0;
        b_rot[idx * 4 + 2] = bn[2] * c1 - bn[3] * s1;
        b_rot[idx * 4 + 3] = bn[2] * s1 + bn[3] * c1;
    }
}

// ===========================================================================
// 8-phase bf16 MFMA NT GEMM (m201 geometry), unchanged.
// ===========================================================================
template <int BIASROW>
__global__ __launch_bounds__(512) void gemm_8p(
    const __hip_bfloat16* __restrict__ A, const __hip_bfloat16* __restrict__ B,
    const float* __restrict__ bias, float* __restrict__ C,
    int M, int N, int K)
{
    __shared__ short lds[65536];
    const short* Ag = (const short*)A;
    const short* Bg = (const short*)B;
    int t = threadIdx.x;
    int lane = t & 63;
    int wid = t >> 6;
    int wm = wid >> 2, wn = wid & 3;

    int nwg = gridDim.x * gridDim.y;
    int flat = blockIdx.y * gridDim.x + blockIdx.x;
    int swz = (flat & 7) * (nwg >> 3) + (flat >> 3);
    int bx = swz % gridDim.x, by = swz / gridDim.x;
    int m0 = by * 256, n0 = bx * 256;
    int T = K >> 6;

    int srow = t >> 3;
    int sc = ((t & 7) ^ (srow & 7)) * 8;
    const short* Asrc[4]; const short* Bsrc[4];
    #pragma unroll
    for (int p = 0; p < 4; ++p) {
        Asrc[p] = Ag + (size_t)(m0 + p * 64 + srow) * K + sc;
        Bsrc[p] = Bg + (size_t)(n0 + p * 64 + srow) * K + sc;
    }

    f32x4 acc[8][4] = {};

    #pragma unroll
    for (int u = 0; u < 2; ++u) {
        short* bA = lds + u * 32768;
        short* bB = bA + 16384;
        size_t ko = (size_t)u * 64;
        #pragma unroll
        for (int p = 0; p < 4; ++p) GLOAD16(Asrc[p] + ko, bA + p * 4096 + t * 8);
        #pragma unroll
        for (int p = 0; p < 4; ++p) GLOAD16(Bsrc[p] + ko, bB + p * 4096 + t * 8);
    }

    for (int tt = 0; tt < T; ++tt) {
        if (tt + 1 < T) { asm volatile("s_waitcnt vmcnt(8)" ::: "memory"); }
        else            { asm volatile("s_waitcnt vmcnt(0)" ::: "memory"); }
        __builtin_amdgcn_s_barrier();
        __builtin_amdgcn_sched_barrier(0);

        const char* Asb = (const char*)(lds + (tt & 1) * 32768);
        const char* Bsb = Asb + 32768;
        short* pA = lds + (tt & 1) * 32768;
        short* pB = pA + 16384;
        bool pf = (tt + 2) < T;
        size_t ko = (size_t)(tt + 2) * 64;

        bf16x8 af[4][2], bfr[4][2];
        // ph0
        #pragma unroll
        for (int f = 0; f < 4; ++f) {
            int r = wm * 128 + f * 16 + (lane & 15);
            #pragma unroll
            for (int ks = 0; ks < 2; ++ks) {
                int cb = ks * 64 + (lane >> 4) * 16;
                af[f][ks] = *(const bf16x8*)(Asb + r * 128 + (cb ^ ((r & 7) << 4)));
            }
        }
        #pragma unroll
        for (int g = 0; g < 2; ++g) {
            int r = wn * 64 + g * 16 + (lane & 15);
            #pragma unroll
            for (int ks = 0; ks < 2; ++ks) {
                int cb = ks * 64 + (lane >> 4) * 16;
                bfr[g][ks] = *(const bf16x8*)(Bsb + r * 128 + (cb ^ ((r & 7) << 4)));
            }
        }
        __builtin_amdgcn_s_barrier();
        __builtin_amdgcn_s_setprio(1);
        #pragma unroll
        for (int f = 0; f < 4; ++f)
            #pragma unroll
            for (int g = 0; g < 2; ++g)
                #pragma unroll
                for (int ks = 0; ks < 2; ++ks)
                    acc[f][g] = __builtin_amdgcn_mfma_f32_16x16x32_bf16(
                        af[f][ks], bfr[g][ks], acc[f][g], 0, 0, 0);
        __builtin_amdgcn_s_setprio(0);
        __builtin_amdgcn_s_barrier();
        // ph1
        #pragma unroll
        for (int g = 2; g < 4; ++g) {
            int r = wn * 64 + g * 16 + (lane & 15);
            #pragma unroll
            for (int ks = 0; ks < 2; ++ks) {
                int cb = ks * 64 + (lane >> 4) * 16;
                bfr[g][ks] = *(const bf16x8*)(Bsb + r * 128 + (cb ^ ((r & 7) << 4)));
            }
        }
        __builtin_amdgcn_s_barrier();
        __builtin_amdgcn_s_setprio(1);
        #pragma unroll
        for (int f = 0; f < 4; ++f)
            #pragma unroll
            for (int g = 2; g < 4; ++g)
                #pragma unroll
                for (int ks = 0; ks < 2; ++ks)
                    acc[f][g] = __builtin_amdgcn_mfma_f32_16x16x32_bf16(
                        af[f][ks], bfr[g][ks], acc[f][g], 0, 0, 0);
        __builtin_amdgcn_s_setprio(0);
        __builtin_amdgcn_s_barrier();
        // ph2
        #pragma unroll
        for (int f = 0; f < 4; ++f) {
            int r = wm * 128 + 64 + f * 16 + (lane & 15);
            #pragma unroll
            for (int ks = 0; ks < 2; ++ks) {
                int cb = ks * 64 + (lane >> 4) * 16;
                af[f][ks] = *(const bf16x8*)(Asb + r * 128 + (cb ^ ((r & 7) << 4)));
            }
        }
        if (pf) {
            #pragma unroll
            for (int p = 0; p < 4; ++p) GLOAD16(Bsrc[p] + ko, pB + p * 4096 + t * 8);
        }
        __builtin_amdgcn_s_barrier();
        __builtin_amdgcn_s_setprio(1);
        #pragma unroll
        for (int f = 0; f < 4; ++f)
            #pragma unroll
            for (int g = 0; g < 2; ++g)
                #pragma unroll
                for (int ks = 0; ks < 2; ++ks)
                    acc[4 + f][g] = __builtin_amdgcn_mfma_f32_16x16x32_bf16(
                        af[f][ks], bfr[g][ks], acc[4 + f][g], 0, 0, 0);
        __builtin_amdgcn_s_setprio(0);
        __builtin_amdgcn_s_barrier();
        // ph3
        if (pf) {
            #pragma unroll
            for (int p = 0; p < 4; ++p) GLOAD16(Asrc[p] + ko, pA + p * 4096 + t * 8);
        }
        __builtin_amdgcn_s_setprio(1);
        #pragma unroll
        for (int f = 0; f < 4; ++f)
            #pragma unroll
            for (int g = 2; g < 4; ++g)
                #pragma unroll
                for (int ks = 0; ks < 2; ++ks)
                    acc[4 + f][g] = __builtin_amdgcn_mfma_f32_16x16x32_bf16(
                        af[f][ks], bfr[g][ks], acc[4 + f][g], 0, 0, 0);
        __builtin_amdgcn_s_setprio(0);
    }

    #pragma unroll
    for (int f = 0; f < 8; ++f) {
        #pragma unroll
        for (int g = 0; g < 4; ++g) {
            int col = n0 + wn * 64 + g * 16 + (lane & 15);
            #pragma unroll
            for (int rg = 0; rg < 4; ++rg) {
                int row = m0 + wm * 128 + f * 16 + (lane >> 4) * 4 + rg;
                float bb = BIASROW ? bias[row] : bias[col];
                C[(size_t)row * N + col] = acc[f][g][rg] + bb;
            }
        }
    }
}

// ===========================================================================
// Kernel 4: fused q-chain + attn + out_win; emits bf16 Pb (= n_x + res_x_base)
// ===========================================================================
__global__ __launch_bounds__(256) void k_attn(
    const float* __restrict__ P, const float* __restrict__ b_buf, const float* __restrict__ b_rot,
    const float* __restrict__ qpw, const float* __restrict__ qpb,
    const float* __restrict__ nqg, const float* __restrict__ nqb,
    const float* __restrict__ qaw, const float* __restrict__ qab,
    const float* __restrict__ pos, __hip_bfloat16* __restrict__ Pb,
    float* __restrict__ attn_out)
{
    __shared__ float bs[16][4], brs[16][4];
    int t = threadIdx.x;
    int wh = blockIdx.y;
    int wi = wh >> 4, h = wh & 15;
    if (t < 64) {
        ((float*)bs)[t]  = b_buf[wh * 64 + t];
        ((float*)brs)[t] = b_rot[wh * 64 + t];
    }
    __syncthreads();
    int p = blockIdx.x * 256 + t;
    int wr = p >> 8, wc = p & 255;
    int gr = ((wi >> 1) << 8) + wr, gc = ((wi & 1) << 8) + wc;
    int y = gr >> 3, hnr = gr & 7, xq = gc >> 3, wnr = gc & 7;
    size_t base = (size_t)(y * 64 + xq) * 4096 + h * 256 + hnr * 8 + wnr;
    float r[4];
    #pragma unroll
    for (int d = 0; d < 4; ++d) r[d] = P[base + (size_t)d * 64];
    float mu = 0.25f * (r[0] + r[1] + r[2] + r[3]);
    float var = 0.25f * ((r[0]-mu)*(r[0]-mu) + (r[1]-mu)*(r[1]-mu) +
                         (r[2]-mu)*(r[2]-mu) + (r[3]-mu)*(r[3]-mu));
    float inv = rsqrtf(var + 1e-5f);
    float xh[4];
    #pragma unroll
    for (int d = 0; d < 4; ++d) xh[d] = (r[d] - mu) * inv * nqg[d] + nqb[d];
    float q4[4];
    #pragma unroll
    for (int d = 0; d < 4; ++d) {
        float a = qpb[d];
        #pragma unroll
        for (int e = 0; e < 4; ++e) a = fmaf(xh[e], qpw[d * 4 + e], a);
        q4[d] = a;
    }
    float z = qab[0];
    #pragma unroll
    for (int d = 0; d < 4; ++d) z = fmaf(q4[d], qaw[d], z);
    float gate = 1.0f / (1.0f + expf(-z));
    float4 pv = *(const float4*)(pos + ((size_t)h * 65536 + p) * 4);
    float v[4];
    v[0] = q4[0] * gate + pv.x * (1.0f - gate);
    v[1] = q4[1] * gate + pv.y * (1.0f - gate);
    v[2] = q4[2] * gate + pv.z * (1.0f - gate);
    v[3] = q4[3] * gate + pv.w * (1.0f - gate);
    float nn = sqrtf(v[0]*v[0] + v[1]*v[1] + v[2]*v[2] + v[3]*v[3]);
    float in2 = 1.0f / fmaxf(nn, 1e-12f);
    #pragma unroll
    for (int d = 0; d < 4; ++d) v[d] *= in2;
    float s0, c0, s1, c1;
    sincosf((float)wr, &s0, &c0);
    sincosf((float)wc, &s1, &c1);
    float qr[4];
    qr[0] = v[0] * c0 - v[1] * s0;
    qr[1] = v[0] * s0 + v[1] * c0;
    qr[2] = v[2] * c1 - v[3] * s1;
    qr[3] = v[2] * s1 + v[3] * c1;
    float arow[16];
    #pragma unroll
    for (int k = 0; k < 16; ++k)
        arow[k] = qr[0] * brs[k][0] + qr[1] * brs[k][1] + qr[2] * brs[k][2] + qr[3] * brs[k][3];
    size_t abase = ((size_t)wh * 65536 + p) * 16;
    #pragma unroll
    for (int kq = 0; kq < 4; ++kq) {
        float4 av;
        av.x = arow[kq * 4 + 0]; av.y = arow[kq * 4 + 1];
        av.z = arow[kq * 4 + 2]; av.w = arow[kq * 4 + 3];
        *(float4*)(attn_out + abase + kq * 4) = av;
    }
    float o[4] = {0.f, 0.f, 0.f, 0.f};
    #pragma unroll
    for (int k = 0; k < 16; ++k) {
        #pragma unroll
        for (int d = 0; d < 4; ++d) o[d] = fmaf(arow[k], bs[k][d], o[d]);
    }
    #pragma unroll
    for (int d = 0; d < 4; ++d)
        Pb[base + (size_t)d * 64] = __float2bfloat16(r[d] + o[d]);
}

// ===========================================================================
extern "C" void kernel_launch(void* const* d_in, const int* in_sizes, int n_in,
                              void* d_out, int out_size, void* d_ws, size_t ws_size,
                              hipStream_t stream)
{
    (void)in_sizes; (void)n_in; (void)out_size; (void)ws_size;
    const float* x    = (const float*)d_in[0];
    const float* xcw  = (const float*)d_in[1];
    const float* xcb  = (const float*)d_in[2];
    const float* rcw  = (const float*)d_in[3];
    const float* rcb  = (const float*)d_in[4];
    const float* pw   = (const float*)d_in[5];
    const float* pb   = (const float*)d_in[6];
    const float* bpw  = (const float*)d_in[7];
    const float* bpb  = (const float*)d_in[8];
    const float* qpw  = (const float*)d_in[9];
    const float* qpb  = (const float*)d_in[10];
    const float* nbg  = (const float*)d_in[11];
    const float* nbb  = (const float*)d_in[12];
    const float* nqg  = (const float*)d_in[13];
    const float* nqb  = (const float*)d_in[14];
    const float* qaw  = (const float*)d_in[15];
    const float* qab  = (const float*)d_in[16];
    const float* pos  = (const float*)d_in[17];
    const float* prw  = (const float*)d_in[18];
    const float* prb  = (const float*)d_in[19];

    float* ws = (float*)d_ws;
    __hip_bfloat16* Xmb   = (__hip_bfloat16*)d_ws;
    __hip_bfloat16* Cb    = (__hip_bfloat16*)(ws + CB_F);
    float*          biasc = ws + BIASC_F;
    float*          b_buf = ws + BBUF_F;
    float*          b_rot = ws + BROT_F;
    float*          P     = ws + P_F;
    __hip_bfloat16* Pb    = (__hip_bfloat16*)(ws + PB_F);
    __hip_bfloat16* prwb  = (__hip_bfloat16*)(ws + PRWB_F);
    float* out = (float*)d_out;

    // front end: cmat + xmap + bchain + cast, one dispatch
    k_front<<<7169, 256, 0, stream>>>(pw, rcw, pb, rcb, Cb, biasc,
                                      x, Xmb, xcw, xcb, bpw, bpb, nbg, nbb,
                                      b_buf, b_rot, prw, prwb);
    // factorized patch conv: M = s(4096), N = co(4096), K = 1024 (972 real)
    gemm_8p<0><<<dim3(16, 16), 512, 0, stream>>>(Xmb, Cb, biasc, P, 4096, 4096, 1024);
    // fused q-chain / attn / out_win; emits bf16 Pb
    k_attn<<<dim3(256, 64), 256, 0, stream>>>(P, b_buf, b_rot, qpw, qpb, nqg, nqb,
                                              qaw, qab, pos, Pb, out + ATTN_OFF);
    // 1x1 proj: M = co(4096), N = s(4096), K = 4096; C = out[co][s], bias per row
    gemm_8p<1><<<dim3(16, 16), 512, 0, stream>>>(prwb, Pb, prb, out, 4096, 4096, 4096);
}

// Round 15
// 427.071 us; speedup vs baseline: 1.0959x; 1.0959x over previous
//
#include <hip/hip_runtime.h>
#include <hip/hip_bf16.h>
#include <math.h>
#include <cstddef>

// ---------------------------------------------------------------------------
// Workspace (float offsets). Total ~151 MB.
//   Xmb   : bf16 [4096 s][1024 k]   floats [0 .. 2,097,152)
//   Cb    : bf16 [4096 co][1024 k]  floats [2,097,152 .. 4,194,304)
//   biasc : f32 [4096]              floats [4,194,304 ..)
//   b_buf : f32 [4096]              floats [4,198,400 ..)
//   b_rot : f32 [4096]              floats [4,202,496 ..)
//   P     : f32 [4096 s][4096 co]   floats [4,206,592 .. 20,983,808)
//   Pb    : bf16 [4096][4096]       floats [20,983,808 .. 29,372,416)
//   prwb  : bf16 [4096][4096]       floats [29,372,416 .. 37,761,024)
// k-index: k = ci*324 + m*18 + n  (ci<3, m<18, n<18; 972 real + 52 zero pad)
// ---------------------------------------------------------------------------
#define CB_F     2097152ull
#define BIASC_F  4194304ull
#define BBUF_F   4198400ull
#define BROT_F   4202496ull
#define P_F      4206592ull
#define PB_F     20983808ull
#define PRWB_F   29372416ull
#define ATTN_OFF 16777216ull

typedef __attribute__((ext_vector_type(8))) short bf16x8;
typedef __attribute__((ext_vector_type(4))) float f32x4;
typedef __attribute__((ext_vector_type(2))) float f32x2;

#define GLOAD16(gsrc, ldst) \
  __builtin_amdgcn_global_load_lds((const __attribute__((address_space(1))) void*)(gsrc), \
                                   (__attribute__((address_space(3))) void*)(ldst), 16, 0, 0)

// ===========================================================================
// Kernel FRONT (one dispatch, 7169 blocks x 256 thr), MANUAL LDS UNION
// (single 26.6 KB pool shared across branches -> 6 blocks/CU like v8):
//   blocks [0,2048)      : C-matrix (cmat v8, pool: Ws@0, Dz@7168, red@26368)
//   blocks [2048,6144)   : Xmap (pool: xs@0)
//   block  6144          : x_feat conv + b-chain (pool: xs@0, xf@768)
//   blocks (6144,7168]   : cast prw f32 -> prwb bf16 (no LDS)
// ===========================================================================
__global__ __launch_bounds__(256) void k_front(
    const float* __restrict__ pw, const float* __restrict__ rcw,
    const float* __restrict__ pb, const float* __restrict__ rcb,
    __hip_bfloat16* __restrict__ Cb, float* __restrict__ biasc,
    const float* __restrict__ x, __hip_bfloat16* __restrict__ Xmb,
    const float* __restrict__ xcw, const float* __restrict__ xcb,
    const float* __restrict__ bpw, const float* __restrict__ bpb,
    const float* __restrict__ nbg, const float* __restrict__ nbb,
    float* __restrict__ b_buf, float* __restrict__ b_rot,
    const float* __restrict__ prw, __hip_bfloat16* __restrict__ prwb)
{
    __shared__ __attribute__((aligned(16))) char smem[26624];
    int t = threadIdx.x;
    int bid = blockIdx.x;

    if (bid < 2048) {
        // ================= cmat v8 (444us winner; pool-carved LDS) =========
        float* Ws  = (float*)smem;            // [64*28] = 7168 B
        float* Dz  = (float*)(smem + 7168);   // [20*20*12] = 19200 B
        float* red = (float*)(smem + 26368);  // [4] = 16 B
        int w = t >> 6, lane = t & 63;
        int co_idx = w >> 1, half = w & 1;
        int co = bid * 2 + co_idx;
        const float* pwc = pw + (size_t)co * 16384;

        for (int i = t; i < 1728; i += 256) Ws[(i / 27) * 28 + (i % 27)] = rcw[i];
        if (t < 64) Ws[t * 28 + 27] = rcb[t];
        for (int i = t; i < 4800; i += 256) Dz[i] = 0.0f;
        __syncthreads();

        float D[2][27];
        #pragma unroll
        for (int q = 0; q < 2; ++q)
            #pragma unroll
            for (int j = 0; j < 27; ++j) D[q][j] = 0.0f;
        float bsum = 0.0f;
        const float* src = pwc + half * 128 + 2 * lane;
        #pragma unroll 4
        for (int c = 0; c < 64; ++c) {
            f32x2 v = *(const f32x2*)(src + c * 256);
            const f32x4* wp = (const f32x4*)&Ws[c * 28];
            #pragma unroll
            for (int q7 = 0; q7 < 7; ++q7) {
                f32x4 wv = wp[q7];                       // uniform ds_read_b128
                #pragma unroll
                for (int e = 0; e < 4; ++e) {
                    int j = q7 * 4 + e;
                    if (j < 27) {
                        D[0][j] = fmaf(wv[e], v.x, D[0][j]);
                        D[1][j] = fmaf(wv[e], v.y, D[1][j]);
                    } else {
                        bsum = fmaf(wv[e], v.x + v.y, bsum);
                    }
                }
            }
        }
        #pragma unroll
        for (int s = 32; s; s >>= 1) bsum += __shfl_down(bsum, s, 64);
        if (lane == 0) red[w] = bsum;
        __syncthreads();
        if (t < 2) biasc[bid * 2 + t] = pb[bid * 2 + t] + red[t * 2] + red[t * 2 + 1];

        for (int p = 0; p < 6; ++p) {
            int pco = p / 3, ci = p % 3;
            __syncthreads();
            if (co_idx == pco) {
                #pragma unroll
                for (int q = 0; q < 2; ++q) {
                    int rs = half * 128 + 2 * lane + q;
                    int r = rs >> 4, s2 = rs & 15;
                    float* dst = &Dz[((r + 2) * 20 + (s2 + 2)) * 12];
                    #pragma unroll
                    for (int u = 0; u < 9; ++u) dst[u] = D[q][ci * 9 + u];
                }
            }
            __syncthreads();
            int cop = bid * 2 + pco;
            if (t < 162) {
                int m = t / 9, n0 = (t % 9) * 2;
                float a0 = 0.0f, a1 = 0.0f;
                #pragma unroll
                for (int ky = 0; ky < 3; ++ky)
                    #pragma unroll
                    for (int kx = 0; kx < 3; ++kx) {
                        int u = ky * 3 + kx;
                        const float* pz = &Dz[((m - ky + 2) * 20 + (n0 - kx + 2)) * 12 + u];
                        a0 += pz[0];
                        a1 += pz[12];
                    }
                size_t cb = (size_t)cop * 1024;
                Cb[cb + ci * 324 + m * 18 + n0]     = __float2bfloat16(a0);
                Cb[cb + ci * 324 + m * 18 + n0 + 1] = __float2bfloat16(a1);
            }
            if (ci == 0 && t >= 162 && t < 214)
                Cb[(size_t)cop * 1024 + 972 + (t - 162)] = __float2bfloat16(0.0f);
        }
        return;
    }

    if (bid > 6144) {
        // ================= cast prw -> prwb (1024 blocks, grid-stride) =====
        long base0 = ((long)(bid - 6145) * 256 + t) * 8;
        for (long i = base0; i < 16777216L; i += 2097152L) {
            float4 v0 = *(const float4*)(prw + i);
            float4 v1 = *(const float4*)(prw + i + 4);
            __hip_bfloat16 h[8] = {__float2bfloat16(v0.x), __float2bfloat16(v0.y),
                                   __float2bfloat16(v0.z), __float2bfloat16(v0.w),
                                   __float2bfloat16(v1.x), __float2bfloat16(v1.y),
                                   __float2bfloat16(v1.z), __float2bfloat16(v1.w)};
            *(ushort4*)(prwb + i)     = *(const ushort4*)h;
            *(ushort4*)(prwb + i + 4) = *(const ushort4*)(h + 4);
        }
        return;
    }

    // shared x tile for xmap / bchain paths (pool-carved)
    float* xs = (float*)smem;               // [3*8*8] = 768 B
    if (t < 192) xs[(t / 64) * 64 + ((t / 8) % 8) * 8 + (t % 8)] = x[t];
    __syncthreads();

    if (bid < 6144) {
        // ================= Xmap =================
        int s = bid - 2048, py = s >> 6, px = s & 63;
        __hip_bfloat16 out4[4];
        #pragma unroll
        for (int u = 0; u < 4; ++u) {
            int k = t * 4 + u;
            float val = 0.0f;
            if (k < 972) {
                int ci = k / 324, r = k % 324, m = r / 18, n = r % 18;
                int row = 16 * py + m - 1, col = 16 * px + n - 1;
                if (row >= 0 && row < 1024 && col >= 0 && col < 1024) {
                    float fu = (row + 0.5f) * 0.0078125f - 0.5f;
                    float fv = (col + 0.5f) * 0.0078125f - 0.5f;
                    float fi = floorf(fu), fj = floorf(fv);
                    float tu = fu - fi, tv = fv - fj;
                    int i0 = (int)fi, j0 = (int)fj;
                    int i0c = min(max(i0, 0), 7), i1c = min(max(i0 + 1, 0), 7);
                    int j0c = min(max(j0, 0), 7), j1c = min(max(j0 + 1, 0), 7);
                    val = (xs[ci * 64 + i0c * 8 + j0c] * (1.f - tv) + xs[ci * 64 + i0c * 8 + j1c] * tv) * (1.f - tu)
                        + (xs[ci * 64 + i1c * 8 + j0c] * (1.f - tv) + xs[ci * 64 + i1c * 8 + j1c] * tv) * tu;
                }
            }
            out4[u] = __float2bfloat16(val);
        }
        *(ushort4*)(Xmb + (size_t)s * 1024 + t * 4) = *(const ushort4*)out4;
        return;
    }

    // ================= bchain (bid == 6144) =================
    float* xf = (float*)(smem + 768);       // [64*8*8] = 16384 B
    for (int o = t; o < 4096; o += 256) {
        int c = o >> 6, i = (o >> 3) & 7, j = o & 7;
        float acc = xcb[c];
        for (int ic = 0; ic < 3; ++ic)
            for (int ky = 0; ky < 3; ++ky)
                for (int kx = 0; kx < 3; ++kx) {
                    int ii = i - 1 + ky, jj = j - 1 + kx;
                    if (ii >= 0 && ii < 8 && jj >= 0 && jj < 8)
                        acc = fmaf(xs[ic * 64 + ii * 8 + jj], xcw[((c * 3 + ic) * 3 + ky) * 3 + kx], acc);
                }
        xf[c * 64 + i * 8 + j] = acc;
    }
    __syncthreads();
    for (int idx = t; idx < 1024; idx += 256) {
        int wi = idx >> 8, h = (idx >> 4) & 15, pp = idx & 15;
        int pr = pp >> 2, pc = pp & 3;
        int gi = 4 * (wi >> 1) + pr, gj = 4 * (wi & 1) + pc;
        float v[4];
        #pragma unroll
        for (int d = 0; d < 4; ++d) v[d] = xf[(h * 4 + d) * 64 + gi * 8 + gj];
        float mu = 0.25f * (v[0] + v[1] + v[2] + v[3]);
        float var = 0.25f * ((v[0]-mu)*(v[0]-mu) + (v[1]-mu)*(v[1]-mu) +
                             (v[2]-mu)*(v[2]-mu) + (v[3]-mu)*(v[3]-mu));
        float inv = rsqrtf(var + 1e-5f);
        float xh[4];
        #pragma unroll
        for (int d = 0; d < 4; ++d) xh[d] = (v[d] - mu) * inv * nbg[d] + nbb[d];
        float bv[4];
        #pragma unroll
        for (int d = 0; d < 4; ++d) {
            float a = bpb[d];
            #pragma unroll
            for (int e = 0; e < 4; ++e) a = fmaf(xh[e], bpw[d * 4 + e], a);
            bv[d] = a;
        }
        #pragma unroll
        for (int d = 0; d < 4; ++d) b_buf[idx * 4 + d] = bv[d];
        float nn = sqrtf(bv[0]*bv[0] + bv[1]*bv[1] + bv[2]*bv[2] + bv[3]*bv[3]);
        float in2 = 1.0f / fmaxf(nn, 1e-12f);
        float bn[4];
        #pragma unroll
        for (int d = 0; d < 4; ++d) bn[d] = bv[d] * in2;
        float s0, c0, s1, c1;
        sincosf((float)pr, &s0, &c0);
        sincosf((float)pc, &s1, &c1);
        b_rot[idx * 4 + 0] = bn[0] * c0 - bn[1] * s0;
        b_rot[idx * 4 + 1] = bn[0] * s0 + bn[1] * c0;
        b_rot[idx * 4 + 2] = bn[2] * c1 - bn[3] * s1;
        b_rot[idx * 4 + 3] = bn[2] * s1 + bn[3] * c1;
    }
}

// ===========================================================================
// 8-phase bf16 MFMA NT GEMM (m201 geometry), unchanged.
// ===========================================================================
template <int BIASROW>
__global__ __launch_bounds__(512) void gemm_8p(
    const __hip_bfloat16* __restrict__ A, const __hip_bfloat16* __restrict__ B,
    const float* __restrict__ bias, float* __restrict__ C,
    int M, int N, int K)
{
    __shared__ short lds[65536];
    const short* Ag = (const short*)A;
    const short* Bg = (const short*)B;
    int t = threadIdx.x;
    int lane = t & 63;
    int wid = t >> 6;
    int wm = wid >> 2, wn = wid & 3;

    int nwg = gridDim.x * gridDim.y;
    int flat = blockIdx.y * gridDim.x + blockIdx.x;
    int swz = (flat & 7) * (nwg >> 3) + (flat >> 3);
    int bx = swz % gridDim.x, by = swz / gridDim.x;
    int m0 = by * 256, n0 = bx * 256;
    int T = K >> 6;

    int srow = t >> 3;
    int sc = ((t & 7) ^ (srow & 7)) * 8;
    const short* Asrc[4]; const short* Bsrc[4];
    #pragma unroll
    for (int p = 0; p < 4; ++p) {
        Asrc[p] = Ag + (size_t)(m0 + p * 64 + srow) * K + sc;
        Bsrc[p] = Bg + (size_t)(n0 + p * 64 + srow) * K + sc;
    }

    f32x4 acc[8][4] = {};

    #pragma unroll
    for (int u = 0; u < 2; ++u) {
        short* bA = lds + u * 32768;
        short* bB = bA + 16384;
        size_t ko = (size_t)u * 64;
        #pragma unroll
        for (int p = 0; p < 4; ++p) GLOAD16(Asrc[p] + ko, bA + p * 4096 + t * 8);
        #pragma unroll
        for (int p = 0; p < 4; ++p) GLOAD16(Bsrc[p] + ko, bB + p * 4096 + t * 8);
    }

    for (int tt = 0; tt < T; ++tt) {
        if (tt + 1 < T) { asm volatile("s_waitcnt vmcnt(8)" ::: "memory"); }
        else            { asm volatile("s_waitcnt vmcnt(0)" ::: "memory"); }
        __builtin_amdgcn_s_barrier();
        __builtin_amdgcn_sched_barrier(0);

        const char* Asb = (const char*)(lds + (tt & 1) * 32768);
        const char* Bsb = Asb + 32768;
        short* pA = lds + (tt & 1) * 32768;
        short* pB = pA + 16384;
        bool pf = (tt + 2) < T;
        size_t ko = (size_t)(tt + 2) * 64;

        bf16x8 af[4][2], bfr[4][2];
        // ph0
        #pragma unroll
        for (int f = 0; f < 4; ++f) {
            int r = wm * 128 + f * 16 + (lane & 15);
            #pragma unroll
            for (int ks = 0; ks < 2; ++ks) {
                int cb = ks * 64 + (lane >> 4) * 16;
                af[f][ks] = *(const bf16x8*)(Asb + r * 128 + (cb ^ ((r & 7) << 4)));
            }
        }
        #pragma unroll
        for (int g = 0; g < 2; ++g) {
            int r = wn * 64 + g * 16 + (lane & 15);
            #pragma unroll
            for (int ks = 0; ks < 2; ++ks) {
                int cb = ks * 64 + (lane >> 4) * 16;
                bfr[g][ks] = *(const bf16x8*)(Bsb + r * 128 + (cb ^ ((r & 7) << 4)));
            }
        }
        __builtin_amdgcn_s_barrier();
        __builtin_amdgcn_s_setprio(1);
        #pragma unroll
        for (int f = 0; f < 4; ++f)
            #pragma unroll
            for (int g = 0; g < 2; ++g)
                #pragma unroll
                for (int ks = 0; ks < 2; ++ks)
                    acc[f][g] = __builtin_amdgcn_mfma_f32_16x16x32_bf16(
                        af[f][ks], bfr[g][ks], acc[f][g], 0, 0, 0);
        __builtin_amdgcn_s_setprio(0);
        __builtin_amdgcn_s_barrier();
        // ph1
        #pragma unroll
        for (int g = 2; g < 4; ++g) {
            int r = wn * 64 + g * 16 + (lane & 15);
            #pragma unroll
            for (int ks = 0; ks < 2; ++ks) {
                int cb = ks * 64 + (lane >> 4) * 16;
                bfr[g][ks] = *(const bf16x8*)(Bsb + r * 128 + (cb ^ ((r & 7) << 4)));
            }
        }
        __builtin_amdgcn_s_barrier();
        __builtin_amdgcn_s_setprio(1);
        #pragma unroll
        for (int f = 0; f < 4; ++f)
            #pragma unroll
            for (int g = 2; g < 4; ++g)
                #pragma unroll
                for (int ks = 0; ks < 2; ++ks)
                    acc[f][g] = __builtin_amdgcn_mfma_f32_16x16x32_bf16(
                        af[f][ks], bfr[g][ks], acc[f][g], 0, 0, 0);
        __builtin_amdgcn_s_setprio(0);
        __builtin_amdgcn_s_barrier();
        // ph2
        #pragma unroll
        for (int f = 0; f < 4; ++f) {
            int r = wm * 128 + 64 + f * 16 + (lane & 15);
            #pragma unroll
            for (int ks = 0; ks < 2; ++ks) {
                int cb = ks * 64 + (lane >> 4) * 16;
                af[f][ks] = *(const bf16x8*)(Asb + r * 128 + (cb ^ ((r & 7) << 4)));
            }
        }
        if (pf) {
            #pragma unroll
            for (int p = 0; p < 4; ++p) GLOAD16(Bsrc[p] + ko, pB + p * 4096 + t * 8);
        }
        __builtin_amdgcn_s_barrier();
        __builtin_amdgcn_s_setprio(1);
        #pragma unroll
        for (int f = 0; f < 4; ++f)
            #pragma unroll
            for (int g = 0; g < 2; ++g)
                #pragma unroll
                for (int ks = 0; ks < 2; ++ks)
                    acc[4 + f][g] = __builtin_amdgcn_mfma_f32_16x16x32_bf16(
                        af[f][ks], bfr[g][ks], acc[4 + f][g], 0, 0, 0);
        __builtin_amdgcn_s_setprio(0);
        __builtin_amdgcn_s_barrier();
        // ph3
        if (pf) {
            #pragma unroll
            for (int p = 0; p < 4; ++p) GLOAD16(Asrc[p] + ko, pA + p * 4096 + t * 8);
        }
        __builtin_amdgcn_s_setprio(1);
        #pragma unroll
        for (int f = 0; f < 4; ++f)
            #pragma unroll
            for (int g = 2; g < 4; ++g)
                #pragma unroll
                for (int ks = 0; ks < 2; ++ks)
                    acc[4 + f][g] = __builtin_amdgcn_mfma_f32_16x16x32_bf16(
                        af[f][ks], bfr[g][ks], acc[4 + f][g], 0, 0, 0);
        __builtin_amdgcn_s_setprio(0);
    }

    #pragma unroll
    for (int f = 0; f < 8; ++f) {
        #pragma unroll
        for (int g = 0; g < 4; ++g) {
            int col = n0 + wn * 64 + g * 16 + (lane & 15);
            #pragma unroll
            for (int rg = 0; rg < 4; ++rg) {
                int row = m0 + wm * 128 + f * 16 + (lane >> 4) * 4 + rg;
                float bb = BIASROW ? bias[row] : bias[col];
                C[(size_t)row * N + col] = acc[f][g][rg] + bb;
            }
        }
    }
}

// ===========================================================================
// Kernel 4: fused q-chain + attn + out_win; emits bf16 Pb (= n_x + res_x_base)
// ===========================================================================
__global__ __launch_bounds__(256) void k_attn(
    const float* __restrict__ P, const float* __restrict__ b_buf, const float* __restrict__ b_rot,
    const float* __restrict__ qpw, const float* __restrict__ qpb,
    const float* __restrict__ nqg, const float* __restrict__ nqb,
    const float* __restrict__ qaw, const float* __restrict__ qab,
    const float* __restrict__ pos, __hip_bfloat16* __restrict__ Pb,
    float* __restrict__ attn_out)
{
    __shared__ float bs[16][4], brs[16][4];
    int t = threadIdx.x;
    int wh = blockIdx.y;
    int wi = wh >> 4, h = wh & 15;
    if (t < 64) {
        ((float*)bs)[t]  = b_buf[wh * 64 + t];
        ((float*)brs)[t] = b_rot[wh * 64 + t];
    }
    __syncthreads();
    int p = blockIdx.x * 256 + t;
    int wr = p >> 8, wc = p & 255;
    int gr = ((wi >> 1) << 8) + wr, gc = ((wi & 1) << 8) + wc;
    int y = gr >> 3, hnr = gr & 7, xq = gc >> 3, wnr = gc & 7;
    size_t base = (size_t)(y * 64 + xq) * 4096 + h * 256 + hnr * 8 + wnr;
    float r[4];
    #pragma unroll
    for (int d = 0; d < 4; ++d) r[d] = P[base + (size_t)d * 64];
    float mu = 0.25f * (r[0] + r[1] + r[2] + r[3]);
    float var = 0.25f * ((r[0]-mu)*(r[0]-mu) + (r[1]-mu)*(r[1]-mu) +
                         (r[2]-mu)*(r[2]-mu) + (r[3]-mu)*(r[3]-mu));
    float inv = rsqrtf(var + 1e-5f);
    float xh[4];
    #pragma unroll
    for (int d = 0; d < 4; ++d) xh[d] = (r[d] - mu) * inv * nqg[d] + nqb[d];
    float q4[4];
    #pragma unroll
    for (int d = 0; d < 4; ++d) {
        float a = qpb[d];
        #pragma unroll
        for (int e = 0; e < 4; ++e) a = fmaf(xh[e], qpw[d * 4 + e], a);
        q4[d] = a;
    }
    float z = qab[0];
    #pragma unroll
    for (int d = 0; d < 4; ++d) z = fmaf(q4[d], qaw[d], z);
    float gate = 1.0f / (1.0f + expf(-z));
    float4 pv = *(const float4*)(pos + ((size_t)h * 65536 + p) * 4);
    float v[4];
    v[0] = q4[0] * gate + pv.x * (1.0f - gate);
    v[1] = q4[1] * gate + pv.y * (1.0f - gate);
    v[2] = q4[2] * gate + pv.z * (1.0f - gate);
    v[3] = q4[3] * gate + pv.w * (1.0f - gate);
    float nn = sqrtf(v[0]*v[0] + v[1]*v[1] + v[2]*v[2] + v[3]*v[3]);
    float in2 = 1.0f / fmaxf(nn, 1e-12f);
    #pragma unroll
    for (int d = 0; d < 4; ++d) v[d] *= in2;
    float s0, c0, s1, c1;
    sincosf((float)wr, &s0, &c0);
    sincosf((float)wc, &s1, &c1);
    float qr[4];
    qr[0] = v[0] * c0 - v[1] * s0;
    qr[1] = v[0] * s0 + v[1] * c0;
    qr[2] = v[2] * c1 - v[3] * s1;
    qr[3] = v[2] * s1 + v[3] * c1;
    float arow[16];
    #pragma unroll
    for (int k = 0; k < 16; ++k)
        arow[k] = qr[0] * brs[k][0] + qr[1] * brs[k][1] + qr[2] * brs[k][2] + qr[3] * brs[k][3];
    size_t abase = ((size_t)wh * 65536 + p) * 16;
    #pragma unroll
    for (int kq = 0; kq < 4; ++kq) {
        float4 av;
        av.x = arow[kq * 4 + 0]; av.y = arow[kq * 4 + 1];
        av.z = arow[kq * 4 + 2]; av.w = arow[kq * 4 + 3];
        *(float4*)(attn_out + abase + kq * 4) = av;
    }
    float o[4] = {0.f, 0.f, 0.f, 0.f};
    #pragma unroll
    for (int k = 0; k < 16; ++k) {
        #pragma unroll
        for (int d = 0; d < 4; ++d) o[d] = fmaf(arow[k], bs[k][d], o[d]);
    }
    #pragma unroll
    for (int d = 0; d < 4; ++d)
        Pb[base + (size_t)d * 64] = __float2bfloat16(r[d] + o[d]);
}

// ===========================================================================
extern "C" void kernel_launch(void* const* d_in, const int* in_sizes, int n_in,
                              void* d_out, int out_size, void* d_ws, size_t ws_size,
                              hipStream_t stream)
{
    (void)in_sizes; (void)n_in; (void)out_size; (void)ws_size;
    const float* x    = (const float*)d_in[0];
    const float* xcw  = (const float*)d_in[1];
    const float* xcb  = (const float*)d_in[2];
    const float* rcw  = (const float*)d_in[3];
    const float* rcb  = (const float*)d_in[4];
    const float* pw   = (const float*)d_in[5];
    const float* pb   = (const float*)d_in[6];
    const float* bpw  = (const float*)d_in[7];
    const float* bpb  = (const float*)d_in[8];
    const float* qpw  = (const float*)d_in[9];
    const float* qpb  = (const float*)d_in[10];
    const float* nbg  = (const float*)d_in[11];
    const float* nbb  = (const float*)d_in[12];
    const float* nqg  = (const float*)d_in[13];
    const float* nqb  = (const float*)d_in[14];
    const float* qaw  = (const float*)d_in[15];
    const float* qab  = (const float*)d_in[16];
    const float* pos  = (const float*)d_in[17];
    const float* prw  = (const float*)d_in[18];
    const float* prb  = (const float*)d_in[19];

    float* ws = (float*)d_ws;
    __hip_bfloat16* Xmb   = (__hip_bfloat16*)d_ws;
    __hip_bfloat16* Cb    = (__hip_bfloat16*)(ws + CB_F);
    float*          biasc = ws + BIASC_F;
    float*          b_buf = ws + BBUF_F;
    float*          b_rot = ws + BROT_F;
    float*          P     = ws + P_F;
    __hip_bfloat16* Pb    = (__hip_bfloat16*)(ws + PB_F);
    __hip_bfloat16* prwb  = (__hip_bfloat16*)(ws + PRWB_F);
    float* out = (float*)d_out;

    // front end: cmat + xmap + bchain + cast, one dispatch (manual LDS union)
    k_front<<<7169, 256, 0, stream>>>(pw, rcw, pb, rcb, Cb, biasc,
                                      x, Xmb, xcw, xcb, bpw, bpb, nbg, nbb,
                                      b_buf, b_rot, prw, prwb);
    // factorized patch conv: M = s(4096), N = co(4096), K = 1024 (972 real)
    gemm_8p<0><<<dim3(16, 16), 512, 0, stream>>>(Xmb, Cb, biasc, P, 4096, 4096, 1024);
    // fused q-chain / attn / out_win; emits bf16 Pb
    k_attn<<<dim3(256, 64), 256, 0, stream>>>(P, b_buf, b_rot, qpw, qpb, nqg, nqb,
                                              qaw, qab, pos, Pb, out + ATTN_OFF);
    // 1x1 proj: M = co(4096), N = s(4096), K = 4096; C = out[co][s], bias per row
    gemm_8p<1><<<dim3(16, 16), 512, 0, stream>>>(prwb, Pb, prb, out, 4096, 4096, 4096);
}

// Round 17
// 419.697 us; speedup vs baseline: 1.1151x; 1.0176x over previous
//
#include <hip/hip_runtime.h>
#include <hip/hip_bf16.h>
#include <math.h>
#include <cstddef>

// ---------------------------------------------------------------------------
// Workspace (float offsets). Total ~151 MB.
//   Xmb   : bf16 [4096 s][1024 k]   floats [0 .. 2,097,152)
//   Cb    : bf16 [4096 co][1024 k]  floats [2,097,152 .. 4,194,304)
//   biasc : f32 [4096]              floats [4,194,304 ..)
//   b_buf : f32 [4096]              floats [4,198,400 ..)
//   b_rot : f32 [4096]              floats [4,202,496 ..)
//   P     : f32 [4096 s][4096 co]   floats [4,206,592 .. 20,983,808)
//   Pb    : bf16 [4096][4096]       floats [20,983,808 .. 29,372,416)
//   prwb  : bf16 [4096][4096]       floats [29,372,416 .. 37,761,024)
// k-index: k = ci*324 + m*18 + n  (ci<3, m<18, n<18; 972 real + 52 zero pad)
// ---------------------------------------------------------------------------
#define CB_F     2097152ull
#define BIASC_F  4194304ull
#define BBUF_F   4198400ull
#define BROT_F   4202496ull
#define P_F      4206592ull
#define PB_F     20983808ull
#define PRWB_F   29372416ull
#define ATTN_OFF 16777216ull

typedef __attribute__((ext_vector_type(8))) short bf16x8;
typedef __attribute__((ext_vector_type(4))) float f32x4;
typedef __attribute__((ext_vector_type(2))) float f32x2;
typedef __attribute__((ext_vector_type(4))) int   i32x4;

#define GLOAD16(gsrc, ldst) \
  __builtin_amdgcn_global_load_lds((const __attribute__((address_space(1))) void*)(gsrc), \
                                   (__attribute__((address_space(3))) void*)(ldst), 16, 0, 0)

// ===========================================================================
// Kernel FRONT (one dispatch, 7169 blocks x 256 thr), MANUAL LDS UNION
// (19.25 KB pool -> 8 blocks/CU):
//   blocks [0,2048)      : C-matrix (cmat v10b: SMEM scalar weight loads,
//                          EARLY-CLOBBER outputs; pool: Dz@0, red@19200)
//   blocks [2048,6144)   : Xmap (pool: xs@0)
//   block  6144          : x_feat conv + b-chain (pool: xs@0, xf@768)
//   blocks (6144,7168]   : cast prw f32 -> prwb bf16 (no LDS)
// ===========================================================================
__global__ __launch_bounds__(256) void k_front(
    const float* __restrict__ pw, const float* __restrict__ rcw,
    const float* __restrict__ pb, const float* __restrict__ rcb,
    __hip_bfloat16* __restrict__ Cb, float* __restrict__ biasc,
    const float* __restrict__ x, __hip_bfloat16* __restrict__ Xmb,
    const float* __restrict__ xcw, const float* __restrict__ xcb,
    const float* __restrict__ bpw, const float* __restrict__ bpb,
    const float* __restrict__ nbg, const float* __restrict__ nbb,
    float* __restrict__ b_buf, float* __restrict__ b_rot,
    const float* __restrict__ prw, __hip_bfloat16* __restrict__ prwb)
{
    __shared__ __attribute__((aligned(16))) char smem[19456];
    int t = threadIdx.x;
    int bid = blockIdx.x;

    if (bid < 2048) {
        // ===== cmat v10b: SMEM weights (scalar pipe), LDS only for Dz ======
        float* Dz  = (float*)smem;            // [20*20*12] = 19200 B
        float* red = (float*)(smem + 19200);  // [4]
        int w = t >> 6, lane = t & 63;
        int co_idx = w >> 1, half = w & 1;
        int co = bid * 2 + co_idx;
        const float* pwc = pw + (size_t)co * 16384;

        for (int i = t; i < 4800; i += 256) Dz[i] = 0.0f;

        float D[2][27];
        #pragma unroll
        for (int q = 0; q < 2; ++q)
            #pragma unroll
            for (int j = 0; j < 27; ++j) D[q][j] = 0.0f;
        float bsum = 0.0f;
        const float* src = pwc + half * 128 + 2 * lane;
        for (int c = 0; c < 64; ++c) {
            f32x2 v = *(const f32x2*)(src + c * 256);        // per-lane VMEM
            const float* wp = rcw + c * 27;                  // uniform
            const float* bp = rcb + c;                       // uniform
            i32x4 a0, a1, a2, a3, a4, a5, a6; int ab;
            asm volatile(
                "s_load_dwordx4 %0, %8, 0x0\n\t"
                "s_load_dwordx4 %1, %8, 0x10\n\t"
                "s_load_dwordx4 %2, %8, 0x20\n\t"
                "s_load_dwordx4 %3, %8, 0x30\n\t"
                "s_load_dwordx4 %4, %8, 0x40\n\t"
                "s_load_dwordx4 %5, %8, 0x50\n\t"
                "s_load_dwordx4 %6, %8, 0x5c\n\t"
                "s_load_dword   %7, %9, 0x0"
                : "=&s"(a0), "=&s"(a1), "=&s"(a2), "=&s"(a3),
                  "=&s"(a4), "=&s"(a5), "=&s"(a6), "=&s"(ab)
                : "s"(wp), "s"(bp));
            asm volatile("s_waitcnt lgkmcnt(0)" ::: "memory");
            __builtin_amdgcn_sched_barrier(0);
            float wj[27];
            #pragma unroll
            for (int k = 0; k < 4; ++k) {
                wj[k]      = __int_as_float(a0[k]);
                wj[4 + k]  = __int_as_float(a1[k]);
                wj[8 + k]  = __int_as_float(a2[k]);
                wj[12 + k] = __int_as_float(a3[k]);
                wj[16 + k] = __int_as_float(a4[k]);
                wj[20 + k] = __int_as_float(a5[k]);
            }
            wj[24] = __int_as_float(a6[1]);
            wj[25] = __int_as_float(a6[2]);
            wj[26] = __int_as_float(a6[3]);
            float rb = __int_as_float(ab);
            #pragma unroll
            for (int j = 0; j < 27; ++j) {
                D[0][j] = fmaf(wj[j], v.x, D[0][j]);
                D[1][j] = fmaf(wj[j], v.y, D[1][j]);
            }
            bsum = fmaf(rb, v.x + v.y, bsum);
        }
        __syncthreads();     // Dz zero-init complete before stage-2 writes
        #pragma unroll
        for (int s = 32; s; s >>= 1) bsum += __shfl_down(bsum, s, 64);
        if (lane == 0) red[w] = bsum;
        __syncthreads();
        if (t < 2) biasc[bid * 2 + t] = pb[bid * 2 + t] + red[t * 2] + red[t * 2 + 1];

        for (int p = 0; p < 6; ++p) {
            int pco = p / 3, ci = p % 3;
            __syncthreads();
            if (co_idx == pco) {
                #pragma unroll
                for (int q = 0; q < 2; ++q) {
                    int rs = half * 128 + 2 * lane + q;
                    int r = rs >> 4, s2 = rs & 15;
                    float* dst = &Dz[((r + 2) * 20 + (s2 + 2)) * 12];
                    #pragma unroll
                    for (int u = 0; u < 9; ++u) dst[u] = D[q][ci * 9 + u];
                }
            }
            __syncthreads();
            int cop = bid * 2 + pco;
            if (t < 162) {
                int m = t / 9, n0 = (t % 9) * 2;
                float a0s = 0.0f, a1s = 0.0f;
                #pragma unroll
                for (int ky = 0; ky < 3; ++ky)
                    #pragma unroll
                    for (int kx = 0; kx < 3; ++kx) {
                        int u = ky * 3 + kx;
                        const float* pz = &Dz[((m - ky + 2) * 20 + (n0 - kx + 2)) * 12 + u];
                        a0s += pz[0];
                        a1s += pz[12];
                    }
                size_t cb = (size_t)cop * 1024;
                Cb[cb + ci * 324 + m * 18 + n0]     = __float2bfloat16(a0s);
                Cb[cb + ci * 324 + m * 18 + n0 + 1] = __float2bfloat16(a1s);
            }
            if (ci == 0 && t >= 162 && t < 214)
                Cb[(size_t)cop * 1024 + 972 + (t - 162)] = __float2bfloat16(0.0f);
        }
        return;
    }

    if (bid > 6144) {
        // ================= cast prw -> prwb (1024 blocks, grid-stride) =====
        long base0 = ((long)(bid - 6145) * 256 + t) * 8;
        for (long i = base0; i < 16777216L; i += 2097152L) {
            float4 v0 = *(const float4*)(prw + i);
            float4 v1 = *(const float4*)(prw + i + 4);
            __hip_bfloat16 h[8] = {__float2bfloat16(v0.x), __float2bfloat16(v0.y),
                                   __float2bfloat16(v0.z), __float2bfloat16(v0.w),
                                   __float2bfloat16(v1.x), __float2bfloat16(v1.y),
                                   __float2bfloat16(v1.z), __float2bfloat16(v1.w)};
            *(ushort4*)(prwb + i)     = *(const ushort4*)h;
            *(ushort4*)(prwb + i + 4) = *(const ushort4*)(h + 4);
        }
        return;
    }

    // shared x tile for xmap / bchain paths (pool-carved)
    float* xs = (float*)smem;               // [3*8*8] = 768 B
    if (t < 192) xs[(t / 64) * 64 + ((t / 8) % 8) * 8 + (t % 8)] = x[t];
    __syncthreads();

    if (bid < 6144) {
        // ================= Xmap =================
        int s = bid - 2048, py = s >> 6, px = s & 63;
        __hip_bfloat16 out4[4];
        #pragma unroll
        for (int u = 0; u < 4; ++u) {
            int k = t * 4 + u;
            float val = 0.0f;
            if (k < 972) {
                int ci = k / 324, r = k % 324, m = r / 18, n = r % 18;
                int row = 16 * py + m - 1, col = 16 * px + n - 1;
                if (row >= 0 && row < 1024 && col >= 0 && col < 1024) {
                    float fu = (row + 0.5f) * 0.0078125f - 0.5f;
                    float fv = (col + 0.5f) * 0.0078125f - 0.5f;
                    float fi = floorf(fu), fj = floorf(fv);
                    float tu = fu - fi, tv = fv - fj;
                    int i0 = (int)fi, j0 = (int)fj;
                    int i0c = min(max(i0, 0), 7), i1c = min(max(i0 + 1, 0), 7);
                    int j0c = min(max(j0, 0), 7), j1c = min(max(j0 + 1, 0), 7);
                    val = (xs[ci * 64 + i0c * 8 + j0c] * (1.f - tv) + xs[ci * 64 + i0c * 8 + j1c] * tv) * (1.f - tu)
                        + (xs[ci * 64 + i1c * 8 + j0c] * (1.f - tv) + xs[ci * 64 + i1c * 8 + j1c] * tv) * tu;
                }
            }
            out4[u] = __float2bfloat16(val);
        }
        *(ushort4*)(Xmb + (size_t)s * 1024 + t * 4) = *(const ushort4*)out4;
        return;
    }

    // ================= bchain (bid == 6144) =================
    float* xf = (float*)(smem + 768);       // [64*8*8] = 16384 B
    for (int o = t; o < 4096; o += 256) {
        int c = o >> 6, i = (o >> 3) & 7, j = o & 7;
        float acc = xcb[c];
        for (int ic = 0; ic < 3; ++ic)
            for (int ky = 0; ky < 3; ++ky)
                for (int kx = 0; kx < 3; ++kx) {
                    int ii = i - 1 + ky, jj = j - 1 + kx;
                    if (ii >= 0 && ii < 8 && jj >= 0 && jj < 8)
                        acc = fmaf(xs[ic * 64 + ii * 8 + jj], xcw[((c * 3 + ic) * 3 + ky) * 3 + kx], acc);
                }
        xf[c * 64 + i * 8 + j] = acc;
    }
    __syncthreads();
    for (int idx = t; idx < 1024; idx += 256) {
        int wi = idx >> 8, h = (idx >> 4) & 15, pp = idx & 15;
        int pr = pp >> 2, pc = pp & 3;
        int gi = 4 * (wi >> 1) + pr, gj = 4 * (wi & 1) + pc;
        float v[4];
        #pragma unroll
        for (int d = 0; d < 4; ++d) v[d] = xf[(h * 4 + d) * 64 + gi * 8 + gj];
        float mu = 0.25f * (v[0] + v[1] + v[2] + v[3]);
        float var = 0.25f * ((v[0]-mu)*(v[0]-mu) + (v[1]-mu)*(v[1]-mu) +
                             (v[2]-mu)*(v[2]-mu) + (v[3]-mu)*(v[3]-mu));
        float inv = rsqrtf(var + 1e-5f);
        float xh[4];
        #pragma unroll
        for (int d = 0; d < 4; ++d) xh[d] = (v[d] - mu) * inv * nbg[d] + nbb[d];
        float bv[4];
        #pragma unroll
        for (int d = 0; d < 4; ++d) {
            float a = bpb[d];
            #pragma unroll
            for (int e = 0; e < 4; ++e) a = fmaf(xh[e], bpw[d * 4 + e], a);
            bv[d] = a;
        }
        #pragma unroll
        for (int d = 0; d < 4; ++d) b_buf[idx * 4 + d] = bv[d];
        float nn = sqrtf(bv[0]*bv[0] + bv[1]*bv[1] + bv[2]*bv[2] + bv[3]*bv[3]);
        float in2 = 1.0f / fmaxf(nn, 1e-12f);
        float bn[4];
        #pragma unroll
        for (int d = 0; d < 4; ++d) bn[d] = bv[d] * in2;
        float s0, c0, s1, c1;
        sincosf((float)pr, &s0, &c0);
        sincosf((float)pc, &s1, &c1);
        b_rot[idx * 4 + 0] = bn[0] * c0 - bn[1] * s0;
        b_rot[idx * 4 + 1] = bn[0] * s0 + bn[1] * c0;
        b_rot[idx * 4 + 2] = bn[2] * c1 - bn[3] * s1;
        b_rot[idx * 4 + 3] = bn[2] * s1 + bn[3] * c1;
    }
}

// ===========================================================================
// 8-phase bf16 MFMA NT GEMM (m201 geometry), unchanged.
// ===========================================================================
template <int BIASROW>
__global__ __launch_bounds__(512) void gemm_8p(
    const __hip_bfloat16* __restrict__ A, const __hip_bfloat16* __restrict__ B,
    const float* __restrict__ bias, float* __restrict__ C,
    int M, int N, int K)
{
    __shared__ short lds[65536];
    const short* Ag = (const short*)A;
    const short* Bg = (const short*)B;
    int t = threadIdx.x;
    int lane = t & 63;
    int wid = t >> 6;
    int wm = wid >> 2, wn = wid & 3;

    int nwg = gridDim.x * gridDim.y;
    int flat = blockIdx.y * gridDim.x + blockIdx.x;
    int swz = (flat & 7) * (nwg >> 3) + (flat >> 3);
    int bx = swz % gridDim.x, by = swz / gridDim.x;
    int m0 = by * 256, n0 = bx * 256;
    int T = K >> 6;

    int srow = t >> 3;
    int sc = ((t & 7) ^ (srow & 7)) * 8;
    const short* Asrc[4]; const short* Bsrc[4];
    #pragma unroll
    for (int p = 0; p < 4; ++p) {
        Asrc[p] = Ag + (size_t)(m0 + p * 64 + srow) * K + sc;
        Bsrc[p] = Bg + (size_t)(n0 + p * 64 + srow) * K + sc;
    }

    f32x4 acc[8][4] = {};

    #pragma unroll
    for (int u = 0; u < 2; ++u) {
        short* bA = lds + u * 32768;
        short* bB = bA + 16384;
        size_t ko = (size_t)u * 64;
        #pragma unroll
        for (int p = 0; p < 4; ++p) GLOAD16(Asrc[p] + ko, bA + p * 4096 + t * 8);
        #pragma unroll
        for (int p = 0; p < 4; ++p) GLOAD16(Bsrc[p] + ko, bB + p * 4096 + t * 8);
    }

    for (int tt = 0; tt < T; ++tt) {
        if (tt + 1 < T) { asm volatile("s_waitcnt vmcnt(8)" ::: "memory"); }
        else            { asm volatile("s_waitcnt vmcnt(0)" ::: "memory"); }
        __builtin_amdgcn_s_barrier();
        __builtin_amdgcn_sched_barrier(0);

        const char* Asb = (const char*)(lds + (tt & 1) * 32768);
        const char* Bsb = Asb + 32768;
        short* pA = lds + (tt & 1) * 32768;
        short* pB = pA + 16384;
        bool pf = (tt + 2) < T;
        size_t ko = (size_t)(tt + 2) * 64;

        bf16x8 af[4][2], bfr[4][2];
        // ph0
        #pragma unroll
        for (int f = 0; f < 4; ++f) {
            int r = wm * 128 + f * 16 + (lane & 15);
            #pragma unroll
            for (int ks = 0; ks < 2; ++ks) {
                int cb = ks * 64 + (lane >> 4) * 16;
                af[f][ks] = *(const bf16x8*)(Asb + r * 128 + (cb ^ ((r & 7) << 4)));
            }
        }
        #pragma unroll
        for (int g = 0; g < 2; ++g) {
            int r = wn * 64 + g * 16 + (lane & 15);
            #pragma unroll
            for (int ks = 0; ks < 2; ++ks) {
                int cb = ks * 64 + (lane >> 4) * 16;
                bfr[g][ks] = *(const bf16x8*)(Bsb + r * 128 + (cb ^ ((r & 7) << 4)));
            }
        }
        __builtin_amdgcn_s_barrier();
        __builtin_amdgcn_s_setprio(1);
        #pragma unroll
        for (int f = 0; f < 4; ++f)
            #pragma unroll
            for (int g = 0; g < 2; ++g)
                #pragma unroll
                for (int ks = 0; ks < 2; ++ks)
                    acc[f][g] = __builtin_amdgcn_mfma_f32_16x16x32_bf16(
                        af[f][ks], bfr[g][ks], acc[f][g], 0, 0, 0);
        __builtin_amdgcn_s_setprio(0);
        __builtin_amdgcn_s_barrier();
        // ph1
        #pragma unroll
        for (int g = 2; g < 4; ++g) {
            int r = wn * 64 + g * 16 + (lane & 15);
            #pragma unroll
            for (int ks = 0; ks < 2; ++ks) {
                int cb = ks * 64 + (lane >> 4) * 16;
                bfr[g][ks] = *(const bf16x8*)(Bsb + r * 128 + (cb ^ ((r & 7) << 4)));
            }
        }
        __builtin_amdgcn_s_barrier();
        __builtin_amdgcn_s_setprio(1);
        #pragma unroll
        for (int f = 0; f < 4; ++f)
            #pragma unroll
            for (int g = 2; g < 4; ++g)
                #pragma unroll
                for (int ks = 0; ks < 2; ++ks)
                    acc[f][g] = __builtin_amdgcn_mfma_f32_16x16x32_bf16(
                        af[f][ks], bfr[g][ks], acc[f][g], 0, 0, 0);
        __builtin_amdgcn_s_setprio(0);
        __builtin_amdgcn_s_barrier();
        // ph2
        #pragma unroll
        for (int f = 0; f < 4; ++f) {
            int r = wm * 128 + 64 + f * 16 + (lane & 15);
            #pragma unroll
            for (int ks = 0; ks < 2; ++ks) {
                int cb = ks * 64 + (lane >> 4) * 16;
                af[f][ks] = *(const bf16x8*)(Asb + r * 128 + (cb ^ ((r & 7) << 4)));
            }
        }
        if (pf) {
            #pragma unroll
            for (int p = 0; p < 4; ++p) GLOAD16(Bsrc[p] + ko, pB + p * 4096 + t * 8);
        }
        __builtin_amdgcn_s_barrier();
        __builtin_amdgcn_s_setprio(1);
        #pragma unroll
        for (int f = 0; f < 4; ++f)
            #pragma unroll
            for (int g = 0; g < 2; ++g)
                #pragma unroll
                for (int ks = 0; ks < 2; ++ks)
                    acc[4 + f][g] = __builtin_amdgcn_mfma_f32_16x16x32_bf16(
                        af[f][ks], bfr[g][ks], acc[4 + f][g], 0, 0, 0);
        __builtin_amdgcn_s_setprio(0);
        __builtin_amdgcn_s_barrier();
        // ph3
        if (pf) {
            #pragma unroll
            for (int p = 0; p < 4; ++p) GLOAD16(Asrc[p] + ko, pA + p * 4096 + t * 8);
        }
        __builtin_amdgcn_s_setprio(1);
        #pragma unroll
        for (int f = 0; f < 4; ++f)
            #pragma unroll
            for (int g = 2; g < 4; ++g)
                #pragma unroll
                for (int ks = 0; ks < 2; ++ks)
                    acc[4 + f][g] = __builtin_amdgcn_mfma_f32_16x16x32_bf16(
                        af[f][ks], bfr[g][ks], acc[4 + f][g], 0, 0, 0);
        __builtin_amdgcn_s_setprio(0);
    }

    #pragma unroll
    for (int f = 0; f < 8; ++f) {
        #pragma unroll
        for (int g = 0; g < 4; ++g) {
            int col = n0 + wn * 64 + g * 16 + (lane & 15);
            #pragma unroll
            for (int rg = 0; rg < 4; ++rg) {
                int row = m0 + wm * 128 + f * 16 + (lane >> 4) * 4 + rg;
                float bb = BIASROW ? bias[row] : bias[col];
                C[(size_t)row * N + col] = acc[f][g][rg] + bb;
            }
        }
    }
}

// ===========================================================================
// Kernel 4: fused q-chain + attn + out_win; emits bf16 Pb (= n_x + res_x_base)
// ===========================================================================
__global__ __launch_bounds__(256) void k_attn(
    const float* __restrict__ P, const float* __restrict__ b_buf, const float* __restrict__ b_rot,
    const float* __restrict__ qpw, const float* __restrict__ qpb,
    const float* __restrict__ nqg, const float* __restrict__ nqb,
    const float* __restrict__ qaw, const float* __restrict__ qab,
    const float* __restrict__ pos, __hip_bfloat16* __restrict__ Pb,
    float* __restrict__ attn_out)
{
    __shared__ float bs[16][4], brs[16][4];
    int t = threadIdx.x;
    int wh = blockIdx.y;
    int wi = wh >> 4, h = wh & 15;
    if (t < 64) {
        ((float*)bs)[t]  = b_buf[wh * 64 + t];
        ((float*)brs)[t] = b_rot[wh * 64 + t];
    }
    __syncthreads();
    int p = blockIdx.x * 256 + t;
    int wr = p >> 8, wc = p & 255;
    int gr = ((wi >> 1) << 8) + wr, gc = ((wi & 1) << 8) + wc;
    int y = gr >> 3, hnr = gr & 7, xq = gc >> 3, wnr = gc & 7;
    size_t base = (size_t)(y * 64 + xq) * 4096 + h * 256 + hnr * 8 + wnr;
    float r[4];
    #pragma unroll
    for (int d = 0; d < 4; ++d) r[d] = P[base + (size_t)d * 64];
    float mu = 0.25f * (r[0] + r[1] + r[2] + r[3]);
    float var = 0.25f * ((r[0]-mu)*(r[0]-mu) + (r[1]-mu)*(r[1]-mu) +
                         (r[2]-mu)*(r[2]-mu) + (r[3]-mu)*(r[3]-mu));
    float inv = rsqrtf(var + 1e-5f);
    float xh[4];
    #pragma unroll
    for (int d = 0; d < 4; ++d) xh[d] = (r[d] - mu) * inv * nqg[d] + nqb[d];
    float q4[4];
    #pragma unroll
    for (int d = 0; d < 4; ++d) {
        float a = qpb[d];
        #pragma unroll
        for (int e = 0; e < 4; ++e) a = fmaf(xh[e], qpw[d * 4 + e], a);
        q4[d] = a;
    }
    float z = qab[0];
    #pragma unroll
    for (int d = 0; d < 4; ++d) z = fmaf(q4[d], qaw[d], z);
    float gate = 1.0f / (1.0f + expf(-z));
    float4 pv = *(const float4*)(pos + ((size_t)h * 65536 + p) * 4);
    float v[4];
    v[0] = q4[0] * gate + pv.x * (1.0f - gate);
    v[1] = q4[1] * gate + pv.y * (1.0f - gate);
    v[2] = q4[2] * gate + pv.z * (1.0f - gate);
    v[3] = q4[3] * gate + pv.w * (1.0f - gate);
    float nn = sqrtf(v[0]*v[0] + v[1]*v[1] + v[2]*v[2] + v[3]*v[3]);
    float in2 = 1.0f / fmaxf(nn, 1e-12f);
    #pragma unroll
    for (int d = 0; d < 4; ++d) v[d] *= in2;
    float s0, c0, s1, c1;
    sincosf((float)wr, &s0, &c0);
    sincosf((float)wc, &s1, &c1);
    float qr[4];
    qr[0] = v[0] * c0 - v[1] * s0;
    qr[1] = v[0] * s0 + v[1] * c0;
    qr[2] = v[2] * c1 - v[3] * s1;
    qr[3] = v[2] * s1 + v[3] * c1;
    float arow[16];
    #pragma unroll
    for (int k = 0; k < 16; ++k)
        arow[k] = qr[0] * brs[k][0] + qr[1] * brs[k][1] + qr[2] * brs[k][2] + qr[3] * brs[k][3];
    size_t abase = ((size_t)wh * 65536 + p) * 16;
    #pragma unroll
    for (int kq = 0; kq < 4; ++kq) {
        float4 av;
        av.x = arow[kq * 4 + 0]; av.y = arow[kq * 4 + 1];
        av.z = arow[kq * 4 + 2]; av.w = arow[kq * 4 + 3];
        *(float4*)(attn_out + abase + kq * 4) = av;
    }
    float o[4] = {0.f, 0.f, 0.f, 0.f};
    #pragma unroll
    for (int k = 0; k < 16; ++k) {
        #pragma unroll
        for (int d = 0; d < 4; ++d) o[d] = fmaf(arow[k], bs[k][d], o[d]);
    }
    #pragma unroll
    for (int d = 0; d < 4; ++d)
        Pb[base + (size_t)d * 64] = __float2bfloat16(r[d] + o[d]);
}

// ===========================================================================
extern "C" void kernel_launch(void* const* d_in, const int* in_sizes, int n_in,
                              void* d_out, int out_size, void* d_ws, size_t ws_size,
                              hipStream_t stream)
{
    (void)in_sizes; (void)n_in; (void)out_size; (void)ws_size;
    const float* x    = (const float*)d_in[0];
    const float* xcw  = (const float*)d_in[1];
    const float* xcb  = (const float*)d_in[2];
    const float* rcw  = (const float*)d_in[3];
    const float* rcb  = (const float*)d_in[4];
    const float* pw   = (const float*)d_in[5];
    const float* pb   = (const float*)d_in[6];
    const float* bpw  = (const float*)d_in[7];
    const float* bpb  = (const float*)d_in[8];
    const float* qpw  = (const float*)d_in[9];
    const float* qpb  = (const float*)d_in[10];
    const float* nbg  = (const float*)d_in[11];
    const float* nbb  = (const float*)d_in[12];
    const float* nqg  = (const float*)d_in[13];
    const float* nqb  = (const float*)d_in[14];
    const float* qaw  = (const float*)d_in[15];
    const float* qab  = (const float*)d_in[16];
    const float* pos  = (const float*)d_in[17];
    const float* prw  = (const float*)d_in[18];
    const float* prb  = (const float*)d_in[19];

    float* ws = (float*)d_ws;
    __hip_bfloat16* Xmb   = (__hip_bfloat16*)d_ws;
    __hip_bfloat16* Cb    = (__hip_bfloat16*)(ws + CB_F);
    float*          biasc = ws + BIASC_F;
    float*          b_buf = ws + BBUF_F;
    float*          b_rot = ws + BROT_F;
    float*          P     = ws + P_F;
    __hip_bfloat16* Pb    = (__hip_bfloat16*)(ws + PB_F);
    __hip_bfloat16* prwb  = (__hip_bfloat16*)(ws + PRWB_F);
    float* out = (float*)d_out;

    // front end: cmat + xmap + bchain + cast, one dispatch (manual LDS union)
    k_front<<<7169, 256, 0, stream>>>(pw, rcw, pb, rcb, Cb, biasc,
                                      x, Xmb, xcw, xcb, bpw, bpb, nbg, nbb,
                                      b_buf, b_rot, prw, prwb);
    // factorized patch conv: M = s(4096), N = co(4096), K = 1024 (972 real)
    gemm_8p<0><<<dim3(16, 16), 512, 0, stream>>>(Xmb, Cb, biasc, P, 4096, 4096, 1024);
    // fused q-chain / attn / out_win; emits bf16 Pb
    k_attn<<<dim3(256, 64), 256, 0, stream>>>(P, b_buf, b_rot, qpw, qpb, nqg, nqb,
                                              qaw, qab, pos, Pb, out + ATTN_OFF);
    // 1x1 proj: M = co(4096), N = s(4096), K = 4096; C = out[co][s], bias per row
    gemm_8p<1><<<dim3(16, 16), 512, 0, stream>>>(prwb, Pb, prb, out, 4096, 4096, 4096);
}